// Round 1
// baseline (5541.330 us; speedup 1.0000x reference)
//
#include <hip/hip_runtime.h>
#include <cmath>

namespace {

constexpr int L   = 1024;
constexpr int D   = 1024;
constexpr int DFF = 4096;
constexpr int NL  = 3;
constexpr int NH  = 16;
constexpr int DH  = 64;
constexpr long LD = (long)L * D;   // 1048576

// ---------------------------------------------------------------------------
// Templated fp32 GEMM: C[z] = act(alpha * A[z]@B[z] + bias[z])
//  - A: [M x K] row-major, leading dim lda, batch stride sA
//  - B: BT=false -> [K x N] (ldb), BT=true -> [N x K] (ldb) i.e. C=A@B^T
//  - all of M,N,K assumed divisible by BM/BN/BK; pointers 16B aligned.
// ACT: 0 none, 1 relu, 2 tanh
// ---------------------------------------------------------------------------
template<int BM, int BN, int BK, int TM, int TN, int ACT, bool BT>
__global__ __launch_bounds__(256)
void gemm_kernel(const float* __restrict__ A, int lda, long sA,
                 const float* __restrict__ B, int ldb, long sB,
                 float* __restrict__ C, int ldc, long sC,
                 const float* __restrict__ bias, long sBias,
                 int K, float alpha)
{
    constexpr int TX = BN / TN;          // threads along N (16)
    __shared__ float As[BK][BM + 4];     // stored transposed: As[k][m]
    __shared__ float Bs[BK][BN + 4];     // Bs[k][n]
    const int tid = threadIdx.x;
    const int tx  = tid % TX;
    const int ty  = tid / TX;
    const float* Ab = A + (long)blockIdx.z * sA;
    const float* Bb = B + (long)blockIdx.z * sB;
    float*       Cb = C + (long)blockIdx.z * sC;
    const int n0 = blockIdx.x * BN;
    const int m0 = blockIdx.y * BM;

    float acc[TM][TN];
#pragma unroll
    for (int i = 0; i < TM; ++i)
#pragma unroll
        for (int j = 0; j < TN; ++j) acc[i][j] = 0.f;

    constexpr int KQ   = BK / 4;              // float4 chunks per k-row
    constexpr int AREP = BM * BK / 4 / 256;
    constexpr int BREP = BN * BK / 4 / 256;

    for (int kt = 0; kt < K; kt += BK) {
        // ---- stage A tile (rows m0..m0+BM, cols kt..kt+BK), transpose to LDS
#pragma unroll
        for (int r = 0; r < AREP; ++r) {
            int idx = r * 256 + tid;
            int m   = idx / KQ;
            int kq  = idx % KQ;
            float4 a = *(const float4*)(Ab + (long)(m0 + m) * lda + kt + kq * 4);
            As[kq * 4 + 0][m] = a.x;
            As[kq * 4 + 1][m] = a.y;
            As[kq * 4 + 2][m] = a.z;
            As[kq * 4 + 3][m] = a.w;
        }
        // ---- stage B tile
        if constexpr (BT) {
#pragma unroll
            for (int r = 0; r < BREP; ++r) {
                int idx = r * 256 + tid;
                int n   = idx / KQ;
                int kq  = idx % KQ;
                float4 b = *(const float4*)(Bb + (long)(n0 + n) * ldb + kt + kq * 4);
                Bs[kq * 4 + 0][n] = b.x;
                Bs[kq * 4 + 1][n] = b.y;
                Bs[kq * 4 + 2][n] = b.z;
                Bs[kq * 4 + 3][n] = b.w;
            }
        } else {
#pragma unroll
            for (int r = 0; r < BREP; ++r) {
                int idx = r * 256 + tid;
                int k   = idx / (BN / 4);
                int nq  = idx % (BN / 4);
                float4 b = *(const float4*)(Bb + (long)(kt + k) * ldb + n0 + nq * 4);
                *(float4*)&Bs[k][nq * 4] = b;
            }
        }
        __syncthreads();

#pragma unroll
        for (int k = 0; k < BK; ++k) {
            float af[TM], bf[TN];
#pragma unroll
            for (int i = 0; i < TM; i += 4)
                *(float4*)&af[i] = *(const float4*)&As[k][ty * TM + i];
#pragma unroll
            for (int j = 0; j < TN; j += 4)
                *(float4*)&bf[j] = *(const float4*)&Bs[k][tx * TN + j];
#pragma unroll
            for (int i = 0; i < TM; ++i)
#pragma unroll
                for (int j = 0; j < TN; ++j)
                    acc[i][j] = fmaf(af[i], bf[j], acc[i][j]);
        }
        __syncthreads();
    }

    float bv[TN];
#pragma unroll
    for (int j = 0; j < TN; ++j)
        bv[j] = bias ? bias[(long)blockIdx.z * sBias + n0 + tx * TN + j] : 0.f;

#pragma unroll
    for (int i = 0; i < TM; ++i) {
        float* crow = Cb + (long)(m0 + ty * TM + i) * ldc + n0 + tx * TN;
#pragma unroll
        for (int j = 0; j < TN; j += 4) {
            float t0 = acc[i][j + 0] * alpha + bv[j + 0];
            float t1 = acc[i][j + 1] * alpha + bv[j + 1];
            float t2 = acc[i][j + 2] * alpha + bv[j + 2];
            float t3 = acc[i][j + 3] * alpha + bv[j + 3];
            if (ACT == 1) {
                t0 = fmaxf(t0, 0.f); t1 = fmaxf(t1, 0.f);
                t2 = fmaxf(t2, 0.f); t3 = fmaxf(t3, 0.f);
            } else if (ACT == 2) {
                t0 = tanhf(t0); t1 = tanhf(t1);
                t2 = tanhf(t2); t3 = tanhf(t3);
            }
            float4 v = {t0, t1, t2, t3};
            *(float4*)(crow + j) = v;
        }
    }
}

// ---------------------------------------------------------------------------
// x[b] = src + sinusoidal PE, replicated to 3 branches
// ---------------------------------------------------------------------------
__global__ void add_pe_kernel(const float* __restrict__ src, float* __restrict__ x)
{
    long idx = (long)blockIdx.x * 256 + threadIdx.x;   // < LD
    int pos = (int)(idx >> 10);
    int d   = (int)(idx & 1023);
    float expnt = (float)(d & ~1) * (1.0f / (float)D);
    float denom = powf(10000.0f, expnt);
    float ang   = (float)pos / denom;
    float pe    = (d & 1) ? cosf(ang) : sinf(ang);
    float v = src[idx] + pe;
    x[idx]          = v;
    x[LD + idx]     = v;
    x[2 * LD + idx] = v;
}

// ---------------------------------------------------------------------------
// Row-wise masked softmax over S[h][i][:], bias computed on the fly.
// branch: 0=uttm 1=samm 2=othm. In-place. One block (256 thr) per (i,h) row.
// ---------------------------------------------------------------------------
__global__ __launch_bounds__(256)
void softmax_mask_kernel(float* __restrict__ S, const int* __restrict__ utt,
                         const int* __restrict__ spk, const int* __restrict__ winp,
                         int branch)
{
    __shared__ float red[8];
    const int i   = blockIdx.x;
    const int h   = blockIdx.y;
    const int tid = threadIdx.x;
    float* row = S + ((long)h * L + i) * L;
    const int window = winp[0];
    const int utti   = utt[i];
    const int spki   = spk[i];
    const int j0 = tid * 4;

    float4 sv = *(float4*)(row + j0);
    float s[4] = {sv.x, sv.y, sv.z, sv.w};
#pragma unroll
    for (int c = 0; c < 4; ++c) {
        int j = j0 + c;
        int dd = j - i;
        bool win  = (dd <= window) && (-dd <= window);
        bool base = win && (utti > 0) && (utt[j] > 0);
        bool same = (spk[j] == spki);
        bool keep = (branch == 0) ? base
                  : (branch == 1) ? (base && same)
                  : (base && (!same || (j == i)));
        s[c] += keep ? 0.f : -1e9f;
    }
    float mx = fmaxf(fmaxf(s[0], s[1]), fmaxf(s[2], s[3]));
    for (int off = 32; off; off >>= 1) mx = fmaxf(mx, __shfl_xor(mx, off));
    if ((tid & 63) == 0) red[tid >> 6] = mx;
    __syncthreads();
    mx = fmaxf(fmaxf(red[0], red[1]), fmaxf(red[2], red[3]));
    __syncthreads();

    float e[4]; float sum = 0.f;
#pragma unroll
    for (int c = 0; c < 4; ++c) { e[c] = expf(s[c] - mx); sum += e[c]; }
    for (int off = 32; off; off >>= 1) sum += __shfl_xor(sum, off);
    if ((tid & 63) == 0) red[tid >> 6] = sum;
    __syncthreads();
    float inv = 1.f / (red[0] + red[1] + red[2] + red[3]);

    float4 o = {e[0] * inv, e[1] * inv, e[2] * inv, e[3] * inv};
    *(float4*)(row + j0) = o;
}

// ---------------------------------------------------------------------------
// LayerNorm with fused residual: out[row] = LN(x[row]+r[row]) * g + b
// One block (256 thr) per row of 1024; param group = row>>10 (branch).
// ---------------------------------------------------------------------------
__global__ __launch_bounds__(256)
void ln_kernel(const float* __restrict__ x, const float* __restrict__ r,
               const float* __restrict__ g, const float* __restrict__ b,
               float* __restrict__ out, long paramStride)
{
    __shared__ float red[8];
    const int row = blockIdx.x;
    const int grp = row >> 10;
    const int tid = threadIdx.x;
    const long base = (long)row * D + tid * 4;

    float4 xv = *(const float4*)(x + base);
    float4 rv = *(const float4*)(r + base);
    float4 t  = {xv.x + rv.x, xv.y + rv.y, xv.z + rv.z, xv.w + rv.w};

    float s = t.x + t.y + t.z + t.w;
    for (int off = 32; off; off >>= 1) s += __shfl_xor(s, off);
    if ((tid & 63) == 0) red[tid >> 6] = s;
    __syncthreads();
    float mean = (red[0] + red[1] + red[2] + red[3]) * (1.f / (float)D);
    __syncthreads();

    float4 dv = {t.x - mean, t.y - mean, t.z - mean, t.w - mean};
    float sq = dv.x * dv.x + dv.y * dv.y + dv.z * dv.z + dv.w * dv.w;
    for (int off = 32; off; off >>= 1) sq += __shfl_xor(sq, off);
    if ((tid & 63) == 0) red[tid >> 6] = sq;
    __syncthreads();
    float var  = (red[0] + red[1] + red[2] + red[3]) * (1.f / (float)D);
    float rstd = rsqrtf(var + 1e-5f);

    const float* gp = g + (long)grp * paramStride + tid * 4;
    const float* bp = b + (long)grp * paramStride + tid * 4;
    float4 gv = *(const float4*)gp;
    float4 bv = *(const float4*)bp;
    float4 o = {dv.x * rstd * gv.x + bv.x, dv.y * rstd * gv.y + bv.y,
                dv.z * rstd * gv.z + bv.z, dv.w * rstd * gv.w + bv.w};
    *(float4*)(out + base) = o;
}

// ---------------------------------------------------------------------------
// s[row] = dot(t[row], v)   (rows = 2*L), one block per row
// ---------------------------------------------------------------------------
__global__ __launch_bounds__(256)
void rowdot_kernel(const float* __restrict__ t, const float* __restrict__ v,
                   float* __restrict__ s)
{
    __shared__ float red[8];
    const int row = blockIdx.x;
    const int tid = threadIdx.x;
    float4 tv = *(const float4*)(t + (long)row * D + tid * 4);
    float4 vv = *(const float4*)(v + tid * 4);
    float p = tv.x * vv.x + tv.y * vv.y + tv.z * vv.z + tv.w * vv.w;
    for (int off = 32; off; off >>= 1) p += __shfl_xor(p, off);
    if ((tid & 63) == 0) red[tid >> 6] = p;
    __syncthreads();
    if (tid == 0) s[row] = red[0] + red[1] + red[2] + red[3];
}

// ---------------------------------------------------------------------------
// out[l,d] = softmax_k(sb[k,l])-weighted sum of h[k,l,d], K=2
// ---------------------------------------------------------------------------
__global__ void combine_kernel(const float* __restrict__ sb, const float* __restrict__ h,
                               float* __restrict__ out)
{
    long idx = (long)blockIdx.x * 256 + threadIdx.x;   // < LD
    int l = (int)(idx >> 10);
    float s0 = sb[l], s1 = sb[L + l];
    float m  = fmaxf(s0, s1);
    float e0 = expf(s0 - m), e1 = expf(s1 - m);
    float inv = 1.f / (e0 + e1);
    out[idx] = (e0 * h[idx] + e1 * h[LD + idx]) * inv;
}

// ---------------------------------------------------------------------------
// logits = x @ W[1024x7] + b ; out = log_softmax(logits). One block per row.
// ---------------------------------------------------------------------------
__global__ __launch_bounds__(256)
void cls_kernel(const float* __restrict__ x, const float* __restrict__ W,
                const float* __restrict__ b, float* __restrict__ out)
{
    __shared__ float red[4][7];
    __shared__ float logit[7];
    const int row = blockIdx.x;
    const int tid = threadIdx.x;
    float p[7] = {0, 0, 0, 0, 0, 0, 0};
    for (int d = tid; d < D; d += 256) {
        float xv = x[(long)row * D + d];
#pragma unroll
        for (int c = 0; c < 7; ++c) p[c] = fmaf(xv, W[d * 7 + c], p[c]);
    }
#pragma unroll
    for (int c = 0; c < 7; ++c) {
        float v = p[c];
        for (int off = 32; off; off >>= 1) v += __shfl_xor(v, off);
        if ((tid & 63) == 0) red[tid >> 6][c] = v;
    }
    __syncthreads();
    if (tid < 7)
        logit[tid] = red[0][tid] + red[1][tid] + red[2][tid] + red[3][tid] + b[tid];
    __syncthreads();
    if (tid == 0) {
        float mx = logit[0];
        for (int c = 1; c < 7; ++c) mx = fmaxf(mx, logit[c]);
        float sum = 0.f;
        for (int c = 0; c < 7; ++c) sum += expf(logit[c] - mx);
        float lse = logf(sum) + mx;
        for (int c = 0; c < 7; ++c) out[(long)row * 7 + c] = logit[c] - lse;
    }
}

} // anonymous namespace

extern "C" void kernel_launch(void* const* d_in, const int* in_sizes, int n_in,
                              void* d_out, int out_size, void* d_ws, size_t ws_size,
                              hipStream_t stream)
{
    (void)in_sizes; (void)n_in; (void)out_size; (void)ws_size;

    const float* src  = (const float*)d_in[0];
    const int*   utt  = (const int*)d_in[1];
    const int*   spk  = (const int*)d_in[2];
    const int*   winp = (const int*)d_in[3];
    const float* Wqkv = (const float*)d_in[4];
    const float* bqkv = (const float*)d_in[5];
    const float* Wo   = (const float*)d_in[6];
    const float* bo   = (const float*)d_in[7];
    const float* g1   = (const float*)d_in[8];
    const float* b1   = (const float*)d_in[9];
    const float* Wf1  = (const float*)d_in[10];
    const float* bf1  = (const float*)d_in[11];
    const float* Wf2  = (const float*)d_in[12];
    const float* bf2  = (const float*)d_in[13];
    const float* g2   = (const float*)d_in[14];
    const float* b2   = (const float*)d_in[15];
    const float* f1W  = (const float*)d_in[16];
    const float* f1b  = (const float*)d_in[17];
    const float* f1v  = (const float*)d_in[18];
    const float* f2W  = (const float*)d_in[19];
    const float* f2b  = (const float*)d_in[20];
    const float* f2v  = (const float*)d_in[21];
    const float* clsW = (const float*)d_in[22];
    const float* clsb = (const float*)d_in[23];
    float* out = (float*)d_out;

    // ---- workspace arena (floats). Total = 34*LD + 2048 ≈ 143 MB ----
    float* ws    = (float*)d_ws;
    float* x     = ws;               // 3*LD   [3][L][D]
    float* qkv   = x + 3 * LD;       // 9*LD   [3][L][3D]
    float* attno = qkv + 9 * LD;     // 3*LD
    float* tmp   = attno + 3 * LD;   // 3*LD
    float* R1    = tmp + 3 * LD;     // 16*LD shared region
    float* sbuf  = R1 + 16 * LD;     // 2*L
    float* S    = R1;                // [16][L][L] per-branch scores (attention phase)
    float* ffn  = R1;                // [3][L][DFF] (FFN phase)
    float* tbuf = R1;                // [2][L][D]  (fusion phase)
    float* h2   = R1 + 2 * LD;       // [2][L][D]  (fusion phase)

    add_pe_kernel<<<LD / 256, 256, 0, stream>>>(src, x);

    for (int l = 0; l < NL; ++l) {
        // QKV projection, all 3 branches batched: [L,D]@[D,3D]
        gemm_kernel<128, 128, 16, 8, 8, 0, false>
            <<<dim3(3 * D / 128, L / 128, 3), 256, 0, stream>>>(
            x, D, LD, Wqkv + (long)l * D * 3 * D, 3 * D, (long)NL * D * 3 * D,
            qkv, 3 * D, 3 * LD, bqkv + (long)l * 3 * D, (long)NL * 3 * D, D, 1.f);

        for (int b = 0; b < 3; ++b) {
            const float* qkvb = qkv + (long)b * 3 * LD;
            // scores: S[h] = q@k^T * 0.125  (NT GEMM, K=64, batched over heads)
            gemm_kernel<128, 128, 16, 8, 8, 0, true>
                <<<dim3(L / 128, L / 128, NH), 256, 0, stream>>>(
                qkvb, 3 * D, 64, qkvb + D, 3 * D, 64,
                S, L, (long)L * L, nullptr, 0, DH, 0.125f);
            // masked softmax, bias computed from utt/spk/window on the fly
            softmax_mask_kernel<<<dim3(L, NH), 256, 0, stream>>>(S, utt, spk, winp, b);
            // O[h] = P@V  (M=1024, N=64, K=1024)
            gemm_kernel<64, 64, 16, 4, 4, 0, false>
                <<<dim3(1, L / 64, NH), 256, 0, stream>>>(
                S, L, (long)L * L, qkvb + 2 * D, 3 * D, 64,
                attno + (long)b * LD, D, 64, nullptr, 0, L, 1.f);
        }

        // output projection
        gemm_kernel<128, 128, 16, 8, 8, 0, false>
            <<<dim3(D / 128, L / 128, 3), 256, 0, stream>>>(
            attno, D, LD, Wo + (long)l * D * D, D, (long)NL * D * D,
            tmp, D, LD, bo + (long)l * D, (long)NL * D, D, 1.f);
        ln_kernel<<<3 * L, 256, 0, stream>>>(x, tmp, g1 + (long)l * D, b1 + (long)l * D,
                                             x, (long)NL * D);
        // FFN
        gemm_kernel<128, 128, 16, 8, 8, 1, false>
            <<<dim3(DFF / 128, L / 128, 3), 256, 0, stream>>>(
            x, D, LD, Wf1 + (long)l * D * DFF, DFF, (long)NL * D * DFF,
            ffn, DFF, (long)L * DFF, bf1 + (long)l * DFF, (long)NL * DFF, D, 1.f);
        gemm_kernel<128, 128, 16, 8, 8, 0, false>
            <<<dim3(D / 128, L / 128, 3), 256, 0, stream>>>(
            ffn, DFF, (long)L * DFF, Wf2 + (long)l * DFF * D, D, (long)NL * DFF * D,
            tmp, D, LD, bf2 + (long)l * D, (long)NL * D, DFF, 1.f);
        ln_kernel<<<3 * L, 256, 0, stream>>>(x, tmp, g2 + (long)l * D, b2 + (long)l * D,
                                             x, (long)NL * D);
    }

    // ---- fusion 1: h = [sm, om] = x[1], x[2] ----
    gemm_kernel<128, 128, 16, 8, 8, 2, false>
        <<<dim3(D / 128, L / 128, 2), 256, 0, stream>>>(
        x + LD, D, LD, f1W, D, 0, tbuf, D, LD, f1b, 0, D, 1.f);
    rowdot_kernel<<<2 * L, 256, 0, stream>>>(tbuf, f1v, sbuf);
    combine_kernel<<<LD / 256, 256, 0, stream>>>(sbuf, x + LD, h2 + LD);   // sp -> h2[1]
    hipMemcpyAsync(h2, x, LD * sizeof(float), hipMemcpyDeviceToDevice, stream); // ct -> h2[0]

    // ---- fusion 2: h = [ct, sp] = h2 ----
    gemm_kernel<128, 128, 16, 8, 8, 2, false>
        <<<dim3(D / 128, L / 128, 2), 256, 0, stream>>>(
        h2, D, LD, f2W, D, 0, tbuf, D, LD, f2b, 0, D, 1.f);
    rowdot_kernel<<<2 * L, 256, 0, stream>>>(tbuf, f2v, sbuf);
    combine_kernel<<<LD / 256, 256, 0, stream>>>(sbuf, h2, tmp);           // fused -> tmp

    // ---- classifier + log_softmax ----
    cls_kernel<<<L, 256, 0, stream>>>(tmp, clsW, clsb, out);
}